// Round 1
// baseline (14135.921 us; speedup 1.0000x reference)
//
#include <hip/hip_runtime.h>

// Persistent-kernel LSTM autoencoder for MI355X.
// 8 groups x 16 WGs x 64 threads (1 wave). Group g owns batches [16g,16g+16).
// WG w owns h-columns [16w,16w+16) => gate rows {nt*256 + 16w + c} nt=i,f,g,o.
// Weights are held as fp16 MFMA B-fragments in VGPRs (rebuilt enc->dec).
// Cross-WG h exchange: relaxed agent-scope atomics through LLC + per-step
// magic flags (no zero-init needed; ws is poisoned 0xAA each launch).
// Sync chain: enc t waits flag(t-1)/sets flag(t); sid 1024=z, 1025=decinit,
// dec t waits 1025+t / sets 1026+t; tail waits 2049. 2050 sids total.

typedef unsigned int u32;
typedef unsigned long long u64;
typedef unsigned short u16;

typedef _Float16 v8h __attribute__((ext_vector_type(8)));
typedef float    v4f __attribute__((ext_vector_type(4)));
typedef u32      v4u __attribute__((ext_vector_type(4)));

union H8 { v8h v; u64 q[2]; v4u u4; _Float16 h[8]; u16 s[8]; };

#define SCOPE_AGENT __HIP_MEMORY_SCOPE_AGENT
#define MG(sid) (0x5EED0000u + (u32)(sid))

// ws layout (bytes)
#define WS_FLAGS   0u          // 2050*8*16 u32 = 1,049,600 B
#define WS_HBUF    1049600u    // [g][par][16][256] fp16 = 131,072 B
#define WS_ZBUF    1180672u    // [g][16][128] fp16     = 32,768 B
#define WS_WOUT    1213440u    // [g][48 frags][64][16B] = 393,216 B

__device__ __forceinline__ float fsig(float x){
  return __builtin_amdgcn_rcpf(1.f + __builtin_amdgcn_exp2f(-1.4426950408889634f*x));
}
__device__ __forceinline__ float ftanh(float x){
  return 1.f - 2.f*__builtin_amdgcn_rcpf(1.f + __builtin_amdgcn_exp2f(2.8853900817779268f*x));
}
__device__ __forceinline__ u16 h2b(_Float16 h){ union{ _Float16 h; u16 b; } u; u.h = h; return u.b; }

__device__ __forceinline__ u32 wait_flags(u32* flags, int sid, int g, int nf, u32 expect){
  u32* f = flags + ((u64)sid*8u + (u64)g)*16u;
  const int l = (int)threadIdx.x;
  u32 v = expect;
  for(;;){
    v = (l < nf) ? __hip_atomic_load(f + l, __ATOMIC_RELAXED, SCOPE_AGENT) : expect;
    if (__all(v == expect)) break;
    __builtin_amdgcn_s_sleep(1);
  }
  return v ^ expect;  // == 0; used as an address-dependency token
}

__device__ __forceinline__ void set_flag(u32* flags, int sid, int g, int w, u32 val){
  if (threadIdx.x == 0)
    __hip_atomic_store(flags + ((u64)sid*8u + (u64)g)*16u + w, val,
                       __ATOMIC_RELEASE, SCOPE_AGENT);
}

// Build the 4x11 B-fragment set (N = [i16|f16|g16|o16], K = [inp 0..95 | h 96..351]).
__device__ __forceinline__ void build_Bw(v8h Bw[4][11], const float* Wih, const float* Whh,
                                         int wcol, int quad){
  #pragma unroll
  for (int nt = 0; nt < 4; ++nt){
    const int n = nt*256 + wcol;
    #pragma unroll
    for (int kt = 0; kt < 11; ++kt){
      const int k0 = kt*32 + quad*8;
      H8 a;
      #pragma unroll
      for (int j = 0; j < 8; ++j){
        const int k = k0 + j;
        float v;
        if (kt < 3) v = (k < 88) ? Wih[n*88 + k] : 0.f;
        else        v = Whh[n*256 + (k - 96)];
        a.h[j] = (_Float16)v;
      }
      Bw[nt][kt] = a.v;
    }
  }
}

__global__ __launch_bounds__(64, 1) void lstm_ae(
    const float* __restrict__ x,
    const float* __restrict__ Wih_e, const float* __restrict__ Whh_e,
    const float* __restrict__ bih_e, const float* __restrict__ bhh_e,
    const float* __restrict__ Wih_d, const float* __restrict__ Whh_d,
    const float* __restrict__ bih_d, const float* __restrict__ bhh_d,
    const float* __restrict__ W_lat, const float* __restrict__ b_lat,
    const float* __restrict__ W_decinit, const float* __restrict__ b_decinit,
    const float* __restrict__ W_out, const float* __restrict__ b_out,
    float* __restrict__ dout, char* __restrict__ ws)
{
  const int l = (int)threadIdx.x;
  const int c = l & 15, quad = l >> 4;
  const int bid = (int)blockIdx.x;
  const int g = bid >> 4, w = bid & 15;
  const int wcol = w*16 + c;

  u32*  flags = (u32*)(ws + WS_FLAGS);
  char* hbufB = ws + WS_HBUF;
  char* zbufB = ws + WS_ZBUF;
  char* mywout = ws + WS_WOUT + (u64)g*49152u;

  __shared__ _Float16 predlds[16*104];

  // ---- prologue: W_out fragment copy into ws (plain stores; the first
  // RELEASE flag (sid 0) write-backs L2 so consumers see them) ----
  #pragma unroll
  for (int fi = 0; fi < 3; ++fi){
    const int fid = w*3 + fi, nt = fid >> 3, kt = fid & 7;
    const int n = nt*16 + c, k0 = kt*32 + quad*8;
    H8 a;
    #pragma unroll
    for (int j = 0; j < 8; ++j){
      float v = (n < 88) ? W_out[n*256 + k0 + j] : 0.f;
      a.h[j] = (_Float16)v;
    }
    *(v4u*)(mywout + (u64)(fid*64 + l)*16u) = a.u4;
  }

  v8h Bw[4][11];
  build_Bw(Bw, Wih_e, Whh_e, wcol, quad);
  float be[4];
  #pragma unroll
  for (int nt = 0; nt < 4; ++nt){ const int n = nt*256 + wcol; be[nt] = bih_e[n] + bhh_e[n]; }

  float cst[4] = {0.f, 0.f, 0.f, 0.f};

  // ================= encoder =================
  #pragma unroll 1
  for (int t = 0; t < 1024; ++t){
    // x_t A-fragments (input is constant; safe to load before the wait)
    H8 Ax[3];
    {
      const float* xb = x + ((u64)(g*16 + c)*1024u + (u64)t)*88u;
      #pragma unroll
      for (int kt = 0; kt < 3; ++kt){
        const int k0 = kt*32 + quad*8;
        if (kt == 2 && quad == 3){ Ax[kt].q[0] = 0; Ax[kt].q[1] = 0; }
        else {
          v4f f0 = *(const v4f*)(xb + k0);
          v4f f1 = *(const v4f*)(xb + k0 + 4);
          #pragma unroll
          for (int j = 0; j < 4; ++j){ Ax[kt].h[j] = (_Float16)f0[j]; Ax[kt].h[j+4] = (_Float16)f1[j]; }
        }
      }
    }
    u32 df = 0;
    if (t > 0) df = wait_flags(flags, t-1, g, 16, MG(t-1));

    v4f acc[4];
    #pragma unroll
    for (int nt = 0; nt < 4; ++nt) acc[nt] = (v4f){0.f,0.f,0.f,0.f};

    #pragma unroll
    for (int kt = 0; kt < 3; ++kt)
      #pragma unroll
      for (int nt = 0; nt < 4; ++nt)
        acc[nt] = __builtin_amdgcn_mfma_f32_16x16x32_f16(Ax[kt].v, Bw[nt][kt], acc[nt], 0, 0, 0);

    if (t > 0){
      const u64* hq = (const u64*)(hbufB + (u64)(g*2 + ((t-1)&1))*8192u + df);
      #pragma unroll
      for (int kt = 0; kt < 8; ++kt){
        H8 a;
        const int qi = c*64 + kt*8 + quad*2;
        a.q[0] = __hip_atomic_load(hq + qi,     __ATOMIC_RELAXED, SCOPE_AGENT);
        a.q[1] = __hip_atomic_load(hq + qi + 1, __ATOMIC_RELAXED, SCOPE_AGENT);
        #pragma unroll
        for (int nt = 0; nt < 4; ++nt)
          acc[nt] = __builtin_amdgcn_mfma_f32_16x16x32_f16(a.v, Bw[nt][kt+3], acc[nt], 0, 0, 0);
      }
    }

    u16* hw = (u16*)(hbufB + (u64)(g*2 + (t&1))*8192u);
    #pragma unroll
    for (int r = 0; r < 4; ++r){
      const float gi = acc[0][r] + be[0];
      const float gf = acc[1][r] + be[1];
      const float gg = acc[2][r] + be[2];
      const float go = acc[3][r] + be[3];
      const float cn = fsig(gf)*cst[r] + fsig(gi)*ftanh(gg);
      cst[r] = cn;
      const float hn = fsig(go)*ftanh(cn);
      const int m = quad*4 + r;
      __hip_atomic_store(hw + m*256 + wcol, h2b((_Float16)hn), __ATOMIC_RELAXED, SCOPE_AGENT);
    }
    set_flag(flags, t, g, w, MG(t));
  }

  // ---- switch weights to decoder ----
  build_Bw(Bw, Wih_d, Whh_d, wcol, quad);
  float bd[4];
  #pragma unroll
  for (int nt = 0; nt < 4; ++nt){ const int n = nt*256 + wcol; bd[nt] = bih_d[n] + bhh_d[n]; }
  float bo[6];
  #pragma unroll
  for (int nt = 0; nt < 6; ++nt){ const int n = nt*16 + c; bo[nt] = (n < 88) ? b_out[n] : 0.f; }

  // ---- latent: z = h_n @ W_lat.T + b_lat  (WGs 0..7, one 16-col tile each) ----
  if (w < 8){
    const u32 dz = wait_flags(flags, 1023, g, 16, MG(1023));
    const u64* hq = (const u64*)(hbufB + (u64)(g*2 + 1)*8192u + dz);
    v4f zacc = (v4f){0.f,0.f,0.f,0.f};
    const int n = w*16 + c;
    #pragma unroll
    for (int kt = 0; kt < 8; ++kt){
      H8 a;
      const int qi = c*64 + kt*8 + quad*2;
      a.q[0] = __hip_atomic_load(hq + qi,     __ATOMIC_RELAXED, SCOPE_AGENT);
      a.q[1] = __hip_atomic_load(hq + qi + 1, __ATOMIC_RELAXED, SCOPE_AGENT);
      H8 b;
      const int k0 = kt*32 + quad*8;
      v4f f0 = *(const v4f*)(W_lat + n*256 + k0);
      v4f f1 = *(const v4f*)(W_lat + n*256 + k0 + 4);
      #pragma unroll
      for (int j = 0; j < 4; ++j){ b.h[j] = (_Float16)f0[j]; b.h[j+4] = (_Float16)f1[j]; }
      zacc = __builtin_amdgcn_mfma_f32_16x16x32_f16(a.v, b.v, zacc, 0, 0, 0);
    }
    const float bl = b_lat[n];
    u16* zb = (u16*)(zbufB + (u64)g*4096u);
    #pragma unroll
    for (int r = 0; r < 4; ++r){
      const int m = quad*4 + r;
      const float zv = zacc[r] + bl;
      __builtin_nontemporal_store(zv, dout + 11534336u + (u64)(g*16 + m)*128u + n);
      __hip_atomic_store(zb + m*128 + n, h2b((_Float16)zv), __ATOMIC_RELAXED, SCOPE_AGENT);
    }
    set_flag(flags, 1024, g, w, MG(1024));
  }

  // ---- decoder init: h_dec0 = z @ W_decinit.T + b_decinit (all 16 WGs) ----
  u32 dd = wait_flags(flags, 1024, g, 8, MG(1024));
  {
    const u64* zq = (const u64*)(zbufB + (u64)g*4096u + dd);
    const int n = wcol;
    v4f da = (v4f){0.f,0.f,0.f,0.f};
    #pragma unroll
    for (int kt = 0; kt < 4; ++kt){
      H8 a;
      const int qi = c*32 + kt*8 + quad*2;
      a.q[0] = __hip_atomic_load(zq + qi,     __ATOMIC_RELAXED, SCOPE_AGENT);
      a.q[1] = __hip_atomic_load(zq + qi + 1, __ATOMIC_RELAXED, SCOPE_AGENT);
      H8 b;
      const int k0 = kt*32 + quad*8;
      v4f f0 = *(const v4f*)(W_decinit + n*128 + k0);
      v4f f1 = *(const v4f*)(W_decinit + n*128 + k0 + 4);
      #pragma unroll
      for (int j = 0; j < 4; ++j){ b.h[j] = (_Float16)f0[j]; b.h[j+4] = (_Float16)f1[j]; }
      da = __builtin_amdgcn_mfma_f32_16x16x32_f16(a.v, b.v, da, 0, 0, 0);
    }
    const float bdi = b_decinit[n];
    u16* hw = (u16*)(hbufB + (u64)(g*2 + 1)*8192u);
    #pragma unroll
    for (int r = 0; r < 4; ++r){
      const int m = quad*4 + r;
      const float hv = da[r] + bdi;
      __hip_atomic_store(hw + m*256 + wcol, h2b((_Float16)hv), __ATOMIC_RELAXED, SCOPE_AGENT);
    }
    set_flag(flags, 1025, g, w, MG(1025));
  }

  #pragma unroll
  for (int r = 0; r < 4; ++r) cst[r] = 0.f;
  const char* wrd = mywout + dd;  // ordered-after decinit wait (covers prologue)

  // ================= decoder =================
  #pragma unroll 1
  for (int t = 0; t < 1024; ++t){
    const u32 df = wait_flags(flags, 1025 + t, g, 16, MG(1025 + t));
    const u64* hq = (const u64*)(hbufB + (u64)(g*2 + ((t+1)&1))*8192u + df);
    H8 Ah[8];
    #pragma unroll
    for (int kt = 0; kt < 8; ++kt){
      const int qi = c*64 + kt*8 + quad*2;
      Ah[kt].q[0] = __hip_atomic_load(hq + qi,     __ATOMIC_RELAXED, SCOPE_AGENT);
      Ah[kt].q[1] = __hip_atomic_load(hq + qi + 1, __ATOMIC_RELAXED, SCOPE_AGENT);
    }

    if (t > 0){
      // pred(t-1) = sigmoid(W_out @ h(t-1) + b_out), computed redundantly per WG
      v4f pacc[6];
      #pragma unroll
      for (int nt = 0; nt < 6; ++nt) pacc[nt] = (v4f){0.f,0.f,0.f,0.f};
      #pragma unroll
      for (int nt = 0; nt < 6; ++nt)
        #pragma unroll
        for (int kt = 0; kt < 8; ++kt){
          H8 b; b.u4 = *(const v4u*)(wrd + (u64)((nt*8 + kt)*64 + l)*16u);
          pacc[nt] = __builtin_amdgcn_mfma_f32_16x16x32_f16(Ah[kt].v, b.v, pacc[nt], 0, 0, 0);
        }
      const bool wr = (w < 11) && ((c >> 3) == (w & 1));
      #pragma unroll
      for (int nt = 0; nt < 6; ++nt)
        #pragma unroll
        for (int r = 0; r < 4; ++r){
          const float pv = fsig(pacc[nt][r] + bo[nt]);
          const int m = quad*4 + r;
          predlds[m*104 + nt*16 + c] = (_Float16)pv;
          if (wr && nt == (w >> 1))
            __builtin_nontemporal_store(pv,
              dout + ((u64)(g*16 + m)*1024u + (u64)(t-1))*88u + 8*w + (c & 7));
        }
    }
    __syncthreads();

    H8 Ap[3];
    if (t == 0){
      #pragma unroll
      for (int kt = 0; kt < 3; ++kt){ Ap[kt].q[0] = 0; Ap[kt].q[1] = 0; }
    } else {
      #pragma unroll
      for (int kt = 0; kt < 3; ++kt)
        Ap[kt].u4 = *(const v4u*)(&predlds[c*104 + kt*32 + quad*8]);
    }

    v4f acc[4];
    #pragma unroll
    for (int nt = 0; nt < 4; ++nt) acc[nt] = (v4f){0.f,0.f,0.f,0.f};
    #pragma unroll
    for (int kt = 0; kt < 3; ++kt)
      #pragma unroll
      for (int nt = 0; nt < 4; ++nt)
        acc[nt] = __builtin_amdgcn_mfma_f32_16x16x32_f16(Ap[kt].v, Bw[nt][kt], acc[nt], 0, 0, 0);
    #pragma unroll
    for (int kt = 0; kt < 8; ++kt)
      #pragma unroll
      for (int nt = 0; nt < 4; ++nt)
        acc[nt] = __builtin_amdgcn_mfma_f32_16x16x32_f16(Ah[kt].v, Bw[nt][kt+3], acc[nt], 0, 0, 0);

    u16* hw = (u16*)(hbufB + (u64)(g*2 + (t&1))*8192u);
    #pragma unroll
    for (int r = 0; r < 4; ++r){
      const float gi = acc[0][r] + bd[0];
      const float gf = acc[1][r] + bd[1];
      const float gg = acc[2][r] + bd[2];
      const float go = acc[3][r] + bd[3];
      const float cn = fsig(gf)*cst[r] + fsig(gi)*ftanh(gg);
      cst[r] = cn;
      const float hn = fsig(go)*ftanh(cn);
      const int m = quad*4 + r;
      __hip_atomic_store(hw + m*256 + wcol, h2b((_Float16)hn), __ATOMIC_RELAXED, SCOPE_AGENT);
    }
    set_flag(flags, 1026 + t, g, w, MG(1026 + t));
  }

  // ---- tail: pred(1023) -> output row 1023 ----
  {
    const u32 df = wait_flags(flags, 2049, g, 16, MG(2049));
    const u64* hq = (const u64*)(hbufB + (u64)(g*2 + 1)*8192u + df);
    H8 Ah[8];
    #pragma unroll
    for (int kt = 0; kt < 8; ++kt){
      const int qi = c*64 + kt*8 + quad*2;
      Ah[kt].q[0] = __hip_atomic_load(hq + qi,     __ATOMIC_RELAXED, SCOPE_AGENT);
      Ah[kt].q[1] = __hip_atomic_load(hq + qi + 1, __ATOMIC_RELAXED, SCOPE_AGENT);
    }
    v4f pacc[6];
    #pragma unroll
    for (int nt = 0; nt < 6; ++nt) pacc[nt] = (v4f){0.f,0.f,0.f,0.f};
    #pragma unroll
    for (int nt = 0; nt < 6; ++nt)
      #pragma unroll
      for (int kt = 0; kt < 8; ++kt){
        H8 b; b.u4 = *(const v4u*)(wrd + (u64)((nt*8 + kt)*64 + l)*16u);
        pacc[nt] = __builtin_amdgcn_mfma_f32_16x16x32_f16(Ah[kt].v, b.v, pacc[nt], 0, 0, 0);
      }
    const bool wr = (w < 11) && ((c >> 3) == (w & 1));
    if (wr){
      const int nt = w >> 1;
      #pragma unroll
      for (int r = 0; r < 4; ++r){
        const float pv = fsig(pacc[nt][r] + bo[nt]);
        const int m = quad*4 + r;
        __builtin_nontemporal_store(pv,
          dout + ((u64)(g*16 + m)*1024u + 1023u)*88u + 8*w + (c & 7));
      }
    }
  }
}

extern "C" void kernel_launch(void* const* d_in, const int* in_sizes, int n_in,
                              void* d_out, int out_size, void* d_ws, size_t ws_size,
                              hipStream_t stream){
  (void)in_sizes; (void)n_in; (void)out_size; (void)ws_size;
  hipLaunchKernelGGL(lstm_ae, dim3(128), dim3(64), 0, stream,
    (const float*)d_in[0],  (const float*)d_in[1],  (const float*)d_in[2],
    (const float*)d_in[3],  (const float*)d_in[4],  (const float*)d_in[5],
    (const float*)d_in[6],  (const float*)d_in[7],  (const float*)d_in[8],
    (const float*)d_in[9],  (const float*)d_in[10], (const float*)d_in[11],
    (const float*)d_in[12], (const float*)d_in[13], (const float*)d_in[14],
    (float*)d_out, (char*)d_ws);
}

// Round 2
// 8882.226 us; speedup vs baseline: 1.5915x; 1.5915x over previous
//
#include <hip/hip_runtime.h>

// Persistent-kernel LSTM autoencoder for MI355X — round 2.
// 8 groups x 16 WGs x 64 threads (1 wave). Group g owns batches [16g,16g+16).
// WG w owns h-columns [16w,16w+16). Weights as fp16 MFMA B-frags in VGPRs.
// h-exchange: per-value TAGGED u32 (tag16|fp16) through the MALL via relaxed
// agent-scope atomics. NO release fences, NO flags, NO wbl2: producers
// fire-and-forget; consumers speculatively load the whole tile and validate
// tags in VALU, retrying until all match (single round trip per step).
// Double-buffer parity: writer of step t+1 implies all WGs consumed t-1.
// Tags: enc h(t)=TAG(t); z=TAG(1024); h0=TAG(1025) in slot 2;
// dec h(t)=TAG(1026+t). 0xAAAA poison never matches any tag.

typedef unsigned int u32;
typedef unsigned long long u64;
typedef unsigned short u16;

typedef _Float16 v8h __attribute__((ext_vector_type(8)));
typedef float    v4f __attribute__((ext_vector_type(4)));
typedef u32      v4u __attribute__((ext_vector_type(4)));

union H8 { v8h v; u64 q[2]; v4u u4; u32 d[4]; _Float16 h[8]; u16 s[8]; };

#define AGT __HIP_MEMORY_SCOPE_AGENT
#define TAG(sid) (0x4000u + (u32)(sid))

// ws layout in u32 units:
//   hbuf: [g][3 slots][16][256] u32  (slot 0/1 = parity, slot 2 = h0)
//   zbuf: [g][16][128] u32
#define HB_U32 12288u
#define ZOFF   98304u

static __device__ __forceinline__ float fsig(float x){
  return __builtin_amdgcn_rcpf(1.f + __builtin_amdgcn_exp2f(-1.4426950408889634f*x));
}
static __device__ __forceinline__ float ftanh(float x){
  return 1.f - 2.f*__builtin_amdgcn_rcpf(1.f + __builtin_amdgcn_exp2f(2.8853900817779268f*x));
}
static __device__ __forceinline__ u32 f2tag(float f, u32 tag){
  union{ _Float16 h; u16 b; } u; u.h = (_Float16)f;
  return (tag << 16) | (u32)u.b;
}
static __device__ __forceinline__ u32 packq(u64 q){
  return ((u32)q & 0xFFFFu) | ((u32)(q >> 32) << 16);
}

// Poll+read one tagged 16x256 tile into 8 A-frags (row = lane&15).
static __device__ __forceinline__ void read_tile256(const u32* tb, u32 tag,
                                                    int c, int quad, H8 Ah[8]){
  const u64* bp = (const u64*)tb + (u64)c*128u + (u64)quad*4u;
  const u64 tp  = ((u64)tag << 16) | ((u64)tag << 48);
  for(;;){
    u64 q[32]; u64 acc = 0;
    #pragma unroll
    for (int kt = 0; kt < 8; ++kt)
      #pragma unroll
      for (int j = 0; j < 4; ++j)
        q[kt*4+j] = __hip_atomic_load(bp + kt*16 + j, __ATOMIC_RELAXED, AGT);
    #pragma unroll
    for (int i = 0; i < 32; ++i) acc |= (q[i] ^ tp);
    if (__all((acc & 0xFFFF0000FFFF0000ull) == 0)){
      #pragma unroll
      for (int kt = 0; kt < 8; ++kt)
        #pragma unroll
        for (int j = 0; j < 4; ++j)
          Ah[kt].d[j] = packq(q[kt*4+j]);
      return;
    }
    __builtin_amdgcn_s_sleep(1);
  }
}

// Poll+read one tagged 16x128 tile into 4 A-frags.
static __device__ __forceinline__ void read_tile128(const u32* tb, u32 tag,
                                                    int c, int quad, H8 Az[4]){
  const u64* bp = (const u64*)tb + (u64)c*64u + (u64)quad*4u;
  const u64 tp  = ((u64)tag << 16) | ((u64)tag << 48);
  for(;;){
    u64 q[16]; u64 acc = 0;
    #pragma unroll
    for (int kt = 0; kt < 4; ++kt)
      #pragma unroll
      for (int j = 0; j < 4; ++j)
        q[kt*4+j] = __hip_atomic_load(bp + kt*16 + j, __ATOMIC_RELAXED, AGT);
    #pragma unroll
    for (int i = 0; i < 16; ++i) acc |= (q[i] ^ tp);
    if (__all((acc & 0xFFFF0000FFFF0000ull) == 0)){
      #pragma unroll
      for (int kt = 0; kt < 4; ++kt)
        #pragma unroll
        for (int j = 0; j < 4; ++j)
          Az[kt].d[j] = packq(q[kt*4+j]);
      return;
    }
    __builtin_amdgcn_s_sleep(1);
  }
}

// 4x11 B-fragments (N=[i16|f16|g16|o16], K=[inp 0..95 pad | h 96..351]).
static __device__ __forceinline__ void build_Bw(v8h Bw[4][11], const float* Wih,
                                                const float* Whh, int wcol, int quad){
  #pragma unroll
  for (int nt = 0; nt < 4; ++nt){
    const int n = nt*256 + wcol;
    #pragma unroll
    for (int kt = 0; kt < 11; ++kt){
      const int k0 = kt*32 + quad*8;
      H8 a;
      #pragma unroll
      for (int j = 0; j < 8; ++j){
        const int k = k0 + j;
        float v;
        if (kt < 3) v = (k < 88) ? Wih[n*88 + k] : 0.f;
        else        v = Whh[n*256 + (k - 96)];
        a.h[j] = (_Float16)v;
      }
      Bw[nt][kt] = a.v;
    }
  }
}

__global__ __launch_bounds__(64, 1) void lstm_ae(
    const float* __restrict__ x,
    const float* __restrict__ Wih_e, const float* __restrict__ Whh_e,
    const float* __restrict__ bih_e, const float* __restrict__ bhh_e,
    const float* __restrict__ Wih_d, const float* __restrict__ Whh_d,
    const float* __restrict__ bih_d, const float* __restrict__ bhh_d,
    const float* __restrict__ W_lat, const float* __restrict__ b_lat,
    const float* __restrict__ W_decinit, const float* __restrict__ b_decinit,
    const float* __restrict__ W_out, const float* __restrict__ b_out,
    float* __restrict__ dout, char* __restrict__ ws)
{
  const int l = (int)threadIdx.x;
  const int c = l & 15, quad = l >> 4;
  const int bid = (int)blockIdx.x;
  const int g = bid >> 4, w = bid & 15;
  const int wcol = w*16 + c;

  u32* wsu = (u32*)ws;
  u32* hb  = wsu + (u64)g*HB_U32;      // 3 slots x 4096 u32
  u32* zb  = wsu + ZOFF + (u64)g*2048u;

  __shared__ v4u      woutlds[3072];    // 48 KB: W_out fp16 B-frags
  __shared__ _Float16 predlds[16*104];

  // ---- prologue: W_out -> LDS fragments (per-WG private, no sync needed
  // beyond the workgroup barrier) ----
  #pragma unroll 4
  for (int fid = 0; fid < 48; ++fid){
    const int nt = fid >> 3, kt = fid & 7;
    const int n = nt*16 + c, k0 = kt*32 + quad*8;
    H8 a;
    #pragma unroll
    for (int j = 0; j < 8; ++j){
      float v = (n < 88) ? W_out[n*256 + k0 + j] : 0.f;
      a.h[j] = (_Float16)v;
    }
    woutlds[fid*64 + l] = a.u4;
  }
  __syncthreads();

  v8h Bw[4][11];
  build_Bw(Bw, Wih_e, Whh_e, wcol, quad);
  float be[4];
  #pragma unroll
  for (int nt = 0; nt < 4; ++nt){ const int n = nt*256 + wcol; be[nt] = bih_e[n] + bhh_e[n]; }

  float cst[4] = {0.f, 0.f, 0.f, 0.f};

  // ================= encoder =================
  #pragma unroll 1
  for (int t = 0; t < 1024; ++t){
    // x_t A-fragments (constant input; issue before the poll so HBM latency hides)
    H8 Ax[3];
    {
      const float* xb = x + ((u64)(g*16 + c)*1024u + (u64)t)*88u;
      #pragma unroll
      for (int kt = 0; kt < 3; ++kt){
        const int k0 = kt*32 + quad*8;
        if (kt == 2 && quad == 3){ Ax[kt].q[0] = 0; Ax[kt].q[1] = 0; }
        else {
          v4f f0 = *(const v4f*)(xb + k0);
          v4f f1 = *(const v4f*)(xb + k0 + 4);
          #pragma unroll
          for (int j = 0; j < 4; ++j){ Ax[kt].h[j] = (_Float16)f0[j]; Ax[kt].h[j+4] = (_Float16)f1[j]; }
        }
      }
    }

    H8 Ah[8];
    if (t > 0) read_tile256(hb + ((t-1)&1)*4096u, TAG(t-1), c, quad, Ah);

    v4f acc[4];
    #pragma unroll
    for (int nt = 0; nt < 4; ++nt) acc[nt] = (v4f){0.f,0.f,0.f,0.f};

    #pragma unroll
    for (int kt = 0; kt < 3; ++kt)
      #pragma unroll
      for (int nt = 0; nt < 4; ++nt)
        acc[nt] = __builtin_amdgcn_mfma_f32_16x16x32_f16(Ax[kt].v, Bw[nt][kt], acc[nt], 0, 0, 0);

    if (t > 0){
      #pragma unroll
      for (int kt = 0; kt < 8; ++kt)
        #pragma unroll
        for (int nt = 0; nt < 4; ++nt)
          acc[nt] = __builtin_amdgcn_mfma_f32_16x16x32_f16(Ah[kt].v, Bw[nt][kt+3], acc[nt], 0, 0, 0);
    }

    u32* hw = hb + (t&1)*4096u;
    const u32 tg = TAG(t);
    #pragma unroll
    for (int r = 0; r < 4; ++r){
      const float gi = acc[0][r] + be[0];
      const float gf = acc[1][r] + be[1];
      const float gg = acc[2][r] + be[2];
      const float go = acc[3][r] + be[3];
      const float cn = fsig(gf)*cst[r] + fsig(gi)*ftanh(gg);
      cst[r] = cn;
      const float hn = fsig(go)*ftanh(cn);
      __hip_atomic_store(hw + (quad*4+r)*256 + wcol, f2tag(hn, tg), __ATOMIC_RELAXED, AGT);
    }
  }

  // ---- switch weights to decoder ----
  build_Bw(Bw, Wih_d, Whh_d, wcol, quad);
  float bd[4];
  #pragma unroll
  for (int nt = 0; nt < 4; ++nt){ const int n = nt*256 + wcol; bd[nt] = bih_d[n] + bhh_d[n]; }
  float bo[6];
  #pragma unroll
  for (int nt = 0; nt < 6; ++nt){ const int n = nt*16 + c; bo[nt] = (n < 88) ? b_out[n] : 0.f; }

  // ---- latent: z = h_n @ W_lat.T + b_lat (WGs 0..7) ----
  if (w < 8){
    H8 Ah[8];
    read_tile256(hb + 4096u, TAG(1023), c, quad, Ah);
    v4f zacc = (v4f){0.f,0.f,0.f,0.f};
    const int n = wcol;  // < 128
    #pragma unroll
    for (int kt = 0; kt < 8; ++kt){
      H8 b;
      const int k0 = kt*32 + quad*8;
      v4f f0 = *(const v4f*)(W_lat + n*256 + k0);
      v4f f1 = *(const v4f*)(W_lat + n*256 + k0 + 4);
      #pragma unroll
      for (int j = 0; j < 4; ++j){ b.h[j] = (_Float16)f0[j]; b.h[j+4] = (_Float16)f1[j]; }
      zacc = __builtin_amdgcn_mfma_f32_16x16x32_f16(Ah[kt].v, b.v, zacc, 0, 0, 0);
    }
    const float bl = b_lat[n];
    #pragma unroll
    for (int r = 0; r < 4; ++r){
      const int m = quad*4 + r;
      const float zv = zacc[r] + bl;
      __builtin_nontemporal_store(zv, dout + 11534336u + (u64)(g*16 + m)*128u + n);
      __hip_atomic_store(zb + m*128 + n, f2tag(zv, TAG(1024)), __ATOMIC_RELAXED, AGT);
    }
  }

  // ---- decoder init: h0 = z @ W_decinit.T + b_decinit (all 16 WGs) ----
  {
    H8 Az[4];
    read_tile128(zb, TAG(1024), c, quad, Az);
    const int n = wcol;
    v4f da = (v4f){0.f,0.f,0.f,0.f};
    #pragma unroll
    for (int kt = 0; kt < 4; ++kt){
      H8 b;
      const int k0 = kt*32 + quad*8;
      v4f f0 = *(const v4f*)(W_decinit + n*128 + k0);
      v4f f1 = *(const v4f*)(W_decinit + n*128 + k0 + 4);
      #pragma unroll
      for (int j = 0; j < 4; ++j){ b.h[j] = (_Float16)f0[j]; b.h[j+4] = (_Float16)f1[j]; }
      da = __builtin_amdgcn_mfma_f32_16x16x32_f16(Az[kt].v, b.v, da, 0, 0, 0);
    }
    const float bdi = b_decinit[n];
    u32* hw = hb + 2u*4096u;  // slot 2
    #pragma unroll
    for (int r = 0; r < 4; ++r){
      const float hv = da[r] + bdi;
      __hip_atomic_store(hw + (quad*4+r)*256 + wcol, f2tag(hv, TAG(1025)), __ATOMIC_RELAXED, AGT);
    }
  }

  #pragma unroll
  for (int r = 0; r < 4; ++r) cst[r] = 0.f;

  // ================= decoder =================
  #pragma unroll 1
  for (int t = 0; t < 1024; ++t){
    const u32 tg = TAG(1025 + t);
    const u32* src = (t == 0) ? (hb + 2u*4096u) : (hb + ((t-1)&1)*4096u);
    H8 Ah[8];
    read_tile256(src, tg, c, quad, Ah);

    if (t > 0){
      // pred(t-1) = sigmoid(W_out @ h(t-1) + b_out), redundant per WG
      v4f pacc[6];
      #pragma unroll
      for (int nt = 0; nt < 6; ++nt) pacc[nt] = (v4f){0.f,0.f,0.f,0.f};
      #pragma unroll
      for (int nt = 0; nt < 6; ++nt)
        #pragma unroll
        for (int kt = 0; kt < 8; ++kt){
          H8 b; b.u4 = woutlds[(nt*8 + kt)*64 + l];
          pacc[nt] = __builtin_amdgcn_mfma_f32_16x16x32_f16(Ah[kt].v, b.v, pacc[nt], 0, 0, 0);
        }
      const bool wr = (w < 11) && ((c >> 3) == (w & 1));
      #pragma unroll
      for (int nt = 0; nt < 6; ++nt)
        #pragma unroll
        for (int r = 0; r < 4; ++r){
          const float pv = fsig(pacc[nt][r] + bo[nt]);
          const int m = quad*4 + r;
          predlds[m*104 + nt*16 + c] = (_Float16)pv;
          if (wr && nt == (w >> 1))
            __builtin_nontemporal_store(pv,
              dout + ((u64)(g*16 + m)*1024u + (u64)(t-1))*88u + 8*w + (c & 7));
        }
    }
    __syncthreads();

    H8 Ap[3];
    if (t == 0){
      #pragma unroll
      for (int kt = 0; kt < 3; ++kt){ Ap[kt].q[0] = 0; Ap[kt].q[1] = 0; }
    } else {
      #pragma unroll
      for (int kt = 0; kt < 3; ++kt)
        Ap[kt].u4 = *(const v4u*)(&predlds[c*104 + kt*32 + quad*8]);
    }

    v4f acc[4];
    #pragma unroll
    for (int nt = 0; nt < 4; ++nt) acc[nt] = (v4f){0.f,0.f,0.f,0.f};
    #pragma unroll
    for (int kt = 0; kt < 3; ++kt)
      #pragma unroll
      for (int nt = 0; nt < 4; ++nt)
        acc[nt] = __builtin_amdgcn_mfma_f32_16x16x32_f16(Ap[kt].v, Bw[nt][kt], acc[nt], 0, 0, 0);
    #pragma unroll
    for (int kt = 0; kt < 8; ++kt)
      #pragma unroll
      for (int nt = 0; nt < 4; ++nt)
        acc[nt] = __builtin_amdgcn_mfma_f32_16x16x32_f16(Ah[kt].v, Bw[nt][kt+3], acc[nt], 0, 0, 0);

    u32* hw = hb + (t&1)*4096u;
    const u32 wtg = TAG(1026 + t);
    #pragma unroll
    for (int r = 0; r < 4; ++r){
      const float gi = acc[0][r] + bd[0];
      const float gf = acc[1][r] + bd[1];
      const float gg = acc[2][r] + bd[2];
      const float go = acc[3][r] + bd[3];
      const float cn = fsig(gf)*cst[r] + fsig(gi)*ftanh(gg);
      cst[r] = cn;
      const float hn = fsig(go)*ftanh(cn);
      __hip_atomic_store(hw + (quad*4+r)*256 + wcol, f2tag(hn, wtg), __ATOMIC_RELAXED, AGT);
    }
  }

  // ---- tail: pred(1023) -> output row 1023 ----
  {
    H8 Ah[8];
    read_tile256(hb + 4096u, TAG(2049), c, quad, Ah);
    v4f pacc[6];
    #pragma unroll
    for (int nt = 0; nt < 6; ++nt) pacc[nt] = (v4f){0.f,0.f,0.f,0.f};
    #pragma unroll
    for (int nt = 0; nt < 6; ++nt)
      #pragma unroll
      for (int kt = 0; kt < 8; ++kt){
        H8 b; b.u4 = woutlds[(nt*8 + kt)*64 + l];
        pacc[nt] = __builtin_amdgcn_mfma_f32_16x16x32_f16(Ah[kt].v, b.v, pacc[nt], 0, 0, 0);
      }
    const bool wr = (w < 11) && ((c >> 3) == (w & 1));
    if (wr){
      const int nt = w >> 1;
      #pragma unroll
      for (int r = 0; r < 4; ++r){
        const float pv = fsig(pacc[nt][r] + bo[nt]);
        const int m = quad*4 + r;
        __builtin_nontemporal_store(pv,
          dout + ((u64)(g*16 + m)*1024u + 1023u)*88u + 8*w + (c & 7));
      }
    }
  }
}

extern "C" void kernel_launch(void* const* d_in, const int* in_sizes, int n_in,
                              void* d_out, int out_size, void* d_ws, size_t ws_size,
                              hipStream_t stream){
  (void)in_sizes; (void)n_in; (void)out_size; (void)ws_size;
  hipLaunchKernelGGL(lstm_ae, dim3(128), dim3(64), 0, stream,
    (const float*)d_in[0],  (const float*)d_in[1],  (const float*)d_in[2],
    (const float*)d_in[3],  (const float*)d_in[4],  (const float*)d_in[5],
    (const float*)d_in[6],  (const float*)d_in[7],  (const float*)d_in[8],
    (const float*)d_in[9],  (const float*)d_in[10], (const float*)d_in[11],
    (const float*)d_in[12], (const float*)d_in[13], (const float*)d_in[14],
    (float*)d_out, (char*)d_ws);
}

// Round 3
// 7903.954 us; speedup vs baseline: 1.7885x; 1.1238x over previous
//
#include <hip/hip_runtime.h>

// Persistent-kernel LSTM autoencoder for MI355X — round 3.
// Identical structure to round 2 (8 groups x 16 WGs x 64 thr, tagged-word
// exchange through MALL, double-buffer parity, no fences/flags), but all
// exchange-buffer traffic now uses batched inline-asm global_load_dwordx4 /
// global_store_dword with sc0+sc1 (L1/L2 bypass) instead of __hip_atomic_*:
// one vmcnt(0) per 16-load tile batch instead of per-word serialized RTTs.

typedef unsigned int u32;
typedef unsigned long long u64;
typedef unsigned short u16;

typedef _Float16 v8h __attribute__((ext_vector_type(8)));
typedef float    v4f __attribute__((ext_vector_type(4)));
typedef u32      v4u __attribute__((ext_vector_type(4)));

union H8 { v8h v; u64 q[2]; v4u u4; u32 d[4]; _Float16 h[8]; u16 s[8]; };

#define TAG(sid) (0x4000u + (u32)(sid))

// ws layout in u32 units:
//   hbuf: [g][3 slots][16][256] u32  (slot 0/1 = parity, slot 2 = h0)
//   zbuf: [g][16][128] u32
#define HB_U32 12288u
#define ZOFF   98304u

static __device__ __forceinline__ float fsig(float x){
  return __builtin_amdgcn_rcpf(1.f + __builtin_amdgcn_exp2f(-1.4426950408889634f*x));
}
static __device__ __forceinline__ float ftanh(float x){
  return 1.f - 2.f*__builtin_amdgcn_rcpf(1.f + __builtin_amdgcn_exp2f(2.8853900817779268f*x));
}
static __device__ __forceinline__ u32 f2tag(float f, u32 tag){
  union{ _Float16 h; u16 b; } u; u.h = (_Float16)f;
  return (tag << 16) | (u32)u.b;
}

// Fire-and-forget store, bypassing L1 (sc0) and XCD-L2 (sc1).
static __device__ __forceinline__ void st_sc01(u32* p, u32 v){
  asm volatile("global_store_dword %0, %1, off sc0 sc1" :: "v"(p), "v"(v) : "memory");
}

// Batched 16-KB tile read (16 x dwordx4, one vmcnt drain), L1/L2 bypass.
static __device__ __forceinline__ void ld_tile256_raw(const u32* p, v4u q[16]){
  asm volatile(
    "global_load_dwordx4 %0, %16, off sc0 sc1\n\t"
    "global_load_dwordx4 %1, %16, off offset:16 sc0 sc1\n\t"
    "global_load_dwordx4 %2, %16, off offset:128 sc0 sc1\n\t"
    "global_load_dwordx4 %3, %16, off offset:144 sc0 sc1\n\t"
    "global_load_dwordx4 %4, %16, off offset:256 sc0 sc1\n\t"
    "global_load_dwordx4 %5, %16, off offset:272 sc0 sc1\n\t"
    "global_load_dwordx4 %6, %16, off offset:384 sc0 sc1\n\t"
    "global_load_dwordx4 %7, %16, off offset:400 sc0 sc1\n\t"
    "global_load_dwordx4 %8, %16, off offset:512 sc0 sc1\n\t"
    "global_load_dwordx4 %9, %16, off offset:528 sc0 sc1\n\t"
    "global_load_dwordx4 %10, %16, off offset:640 sc0 sc1\n\t"
    "global_load_dwordx4 %11, %16, off offset:656 sc0 sc1\n\t"
    "global_load_dwordx4 %12, %16, off offset:768 sc0 sc1\n\t"
    "global_load_dwordx4 %13, %16, off offset:784 sc0 sc1\n\t"
    "global_load_dwordx4 %14, %16, off offset:896 sc0 sc1\n\t"
    "global_load_dwordx4 %15, %16, off offset:912 sc0 sc1\n\t"
    "s_waitcnt vmcnt(0)"
    : "=v"(q[0]), "=v"(q[1]), "=v"(q[2]), "=v"(q[3]),
      "=v"(q[4]), "=v"(q[5]), "=v"(q[6]), "=v"(q[7]),
      "=v"(q[8]), "=v"(q[9]), "=v"(q[10]), "=v"(q[11]),
      "=v"(q[12]), "=v"(q[13]), "=v"(q[14]), "=v"(q[15])
    : "v"(p)
    : "memory");
}

static __device__ __forceinline__ void ld_tile128_raw(const u32* p, v4u q[8]){
  asm volatile(
    "global_load_dwordx4 %0, %8, off sc0 sc1\n\t"
    "global_load_dwordx4 %1, %8, off offset:16 sc0 sc1\n\t"
    "global_load_dwordx4 %2, %8, off offset:128 sc0 sc1\n\t"
    "global_load_dwordx4 %3, %8, off offset:144 sc0 sc1\n\t"
    "global_load_dwordx4 %4, %8, off offset:256 sc0 sc1\n\t"
    "global_load_dwordx4 %5, %8, off offset:272 sc0 sc1\n\t"
    "global_load_dwordx4 %6, %8, off offset:384 sc0 sc1\n\t"
    "global_load_dwordx4 %7, %8, off offset:400 sc0 sc1\n\t"
    "s_waitcnt vmcnt(0)"
    : "=v"(q[0]), "=v"(q[1]), "=v"(q[2]), "=v"(q[3]),
      "=v"(q[4]), "=v"(q[5]), "=v"(q[6]), "=v"(q[7])
    : "v"(p)
    : "memory");
}

// Poll+read one tagged 16x256 tile into 8 A-frags (row = lane&15).
static __device__ __forceinline__ void read_tile256(const u32* tb, u32 tag,
                                                    int c, int quad, H8 Ah[8]){
  const u32* p = tb + c*256 + quad*8;
  const u32 tmask = tag << 16;
  for(;;){
    v4u q[16];
    ld_tile256_raw(p, q);
    u32 bad = 0;
    #pragma unroll
    for (int i = 0; i < 16; ++i)
      #pragma unroll
      for (int j = 0; j < 4; ++j)
        bad |= (q[i][j] ^ tmask);
    if (__all((bad & 0xFFFF0000u) == 0)){
      #pragma unroll
      for (int kt = 0; kt < 8; ++kt){
        const v4u a = q[2*kt], b = q[2*kt+1];
        Ah[kt].d[0] = (a[0] & 0xFFFFu) | (a[1] << 16);
        Ah[kt].d[1] = (a[2] & 0xFFFFu) | (a[3] << 16);
        Ah[kt].d[2] = (b[0] & 0xFFFFu) | (b[1] << 16);
        Ah[kt].d[3] = (b[2] & 0xFFFFu) | (b[3] << 16);
      }
      return;
    }
    __builtin_amdgcn_s_sleep(1);
  }
}

// Poll+read one tagged 16x128 tile into 4 A-frags.
static __device__ __forceinline__ void read_tile128(const u32* tb, u32 tag,
                                                    int c, int quad, H8 Az[4]){
  const u32* p = tb + c*128 + quad*8;
  const u32 tmask = tag << 16;
  for(;;){
    v4u q[8];
    ld_tile128_raw(p, q);
    u32 bad = 0;
    #pragma unroll
    for (int i = 0; i < 8; ++i)
      #pragma unroll
      for (int j = 0; j < 4; ++j)
        bad |= (q[i][j] ^ tmask);
    if (__all((bad & 0xFFFF0000u) == 0)){
      #pragma unroll
      for (int kt = 0; kt < 4; ++kt){
        const v4u a = q[2*kt], b = q[2*kt+1];
        Az[kt].d[0] = (a[0] & 0xFFFFu) | (a[1] << 16);
        Az[kt].d[1] = (a[2] & 0xFFFFu) | (a[3] << 16);
        Az[kt].d[2] = (b[0] & 0xFFFFu) | (b[1] << 16);
        Az[kt].d[3] = (b[2] & 0xFFFFu) | (b[3] << 16);
      }
      return;
    }
    __builtin_amdgcn_s_sleep(1);
  }
}

// 4x11 B-fragments (N=[i16|f16|g16|o16], K=[inp 0..95 pad | h 96..351]).
static __device__ __forceinline__ void build_Bw(v8h Bw[4][11], const float* Wih,
                                                const float* Whh, int wcol, int quad){
  #pragma unroll
  for (int nt = 0; nt < 4; ++nt){
    const int n = nt*256 + wcol;
    #pragma unroll
    for (int kt = 0; kt < 11; ++kt){
      const int k0 = kt*32 + quad*8;
      H8 a;
      #pragma unroll
      for (int j = 0; j < 8; ++j){
        const int k = k0 + j;
        float v;
        if (kt < 3) v = (k < 88) ? Wih[n*88 + k] : 0.f;
        else        v = Whh[n*256 + (k - 96)];
        a.h[j] = (_Float16)v;
      }
      Bw[nt][kt] = a.v;
    }
  }
}

__global__ __launch_bounds__(64, 1) void lstm_ae(
    const float* __restrict__ x,
    const float* __restrict__ Wih_e, const float* __restrict__ Whh_e,
    const float* __restrict__ bih_e, const float* __restrict__ bhh_e,
    const float* __restrict__ Wih_d, const float* __restrict__ Whh_d,
    const float* __restrict__ bih_d, const float* __restrict__ bhh_d,
    const float* __restrict__ W_lat, const float* __restrict__ b_lat,
    const float* __restrict__ W_decinit, const float* __restrict__ b_decinit,
    const float* __restrict__ W_out, const float* __restrict__ b_out,
    float* __restrict__ dout, char* __restrict__ ws)
{
  const int l = (int)threadIdx.x;
  const int c = l & 15, quad = l >> 4;
  const int bid = (int)blockIdx.x;
  const int g = bid >> 4, w = bid & 15;
  const int wcol = w*16 + c;

  u32* wsu = (u32*)ws;
  u32* hb  = wsu + (u64)g*HB_U32;      // 3 slots x 4096 u32
  u32* zb  = wsu + ZOFF + (u64)g*2048u;

  __shared__ v4u      woutlds[3072];    // 48 KB: W_out fp16 B-frags
  __shared__ _Float16 predlds[16*104];

  // ---- prologue: W_out -> LDS fragments ----
  #pragma unroll 4
  for (int fid = 0; fid < 48; ++fid){
    const int nt = fid >> 3, kt = fid & 7;
    const int n = nt*16 + c, k0 = kt*32 + quad*8;
    H8 a;
    #pragma unroll
    for (int j = 0; j < 8; ++j){
      float v = (n < 88) ? W_out[n*256 + k0 + j] : 0.f;
      a.h[j] = (_Float16)v;
    }
    woutlds[fid*64 + l] = a.u4;
  }
  __syncthreads();

  v8h Bw[4][11];
  build_Bw(Bw, Wih_e, Whh_e, wcol, quad);
  float be[4];
  #pragma unroll
  for (int nt = 0; nt < 4; ++nt){ const int n = nt*256 + wcol; be[nt] = bih_e[n] + bhh_e[n]; }

  float cst[4] = {0.f, 0.f, 0.f, 0.f};

  // ================= encoder =================
  #pragma unroll 1
  for (int t = 0; t < 1024; ++t){
    // x_t A-fragments (constant input; issue before the poll so HBM latency hides)
    H8 Ax[3];
    {
      const float* xb = x + ((u64)(g*16 + c)*1024u + (u64)t)*88u;
      #pragma unroll
      for (int kt = 0; kt < 3; ++kt){
        const int k0 = kt*32 + quad*8;
        if (kt == 2 && quad == 3){ Ax[kt].q[0] = 0; Ax[kt].q[1] = 0; }
        else {
          v4f f0 = *(const v4f*)(xb + k0);
          v4f f1 = *(const v4f*)(xb + k0 + 4);
          #pragma unroll
          for (int j = 0; j < 4; ++j){ Ax[kt].h[j] = (_Float16)f0[j]; Ax[kt].h[j+4] = (_Float16)f1[j]; }
        }
      }
    }

    H8 Ah[8];
    if (t > 0) read_tile256(hb + ((t-1)&1)*4096u, TAG(t-1), c, quad, Ah);

    v4f acc[4];
    #pragma unroll
    for (int nt = 0; nt < 4; ++nt) acc[nt] = (v4f){0.f,0.f,0.f,0.f};

    #pragma unroll
    for (int kt = 0; kt < 3; ++kt)
      #pragma unroll
      for (int nt = 0; nt < 4; ++nt)
        acc[nt] = __builtin_amdgcn_mfma_f32_16x16x32_f16(Ax[kt].v, Bw[nt][kt], acc[nt], 0, 0, 0);

    if (t > 0){
      #pragma unroll
      for (int kt = 0; kt < 8; ++kt)
        #pragma unroll
        for (int nt = 0; nt < 4; ++nt)
          acc[nt] = __builtin_amdgcn_mfma_f32_16x16x32_f16(Ah[kt].v, Bw[nt][kt+3], acc[nt], 0, 0, 0);
    }

    u32* hw = hb + (t&1)*4096u;
    const u32 tg = TAG(t);
    #pragma unroll
    for (int r = 0; r < 4; ++r){
      const float gi = acc[0][r] + be[0];
      const float gf = acc[1][r] + be[1];
      const float gg = acc[2][r] + be[2];
      const float go = acc[3][r] + be[3];
      const float cn = fsig(gf)*cst[r] + fsig(gi)*ftanh(gg);
      cst[r] = cn;
      const float hn = fsig(go)*ftanh(cn);
      st_sc01(hw + (quad*4+r)*256 + wcol, f2tag(hn, tg));
    }
  }

  // ---- switch weights to decoder ----
  build_Bw(Bw, Wih_d, Whh_d, wcol, quad);
  float bd[4];
  #pragma unroll
  for (int nt = 0; nt < 4; ++nt){ const int n = nt*256 + wcol; bd[nt] = bih_d[n] + bhh_d[n]; }
  float bo[6];
  #pragma unroll
  for (int nt = 0; nt < 6; ++nt){ const int n = nt*16 + c; bo[nt] = (n < 88) ? b_out[n] : 0.f; }

  // ---- latent: z = h_n @ W_lat.T + b_lat (WGs 0..7) ----
  if (w < 8){
    H8 Ah[8];
    read_tile256(hb + 4096u, TAG(1023), c, quad, Ah);
    v4f zacc = (v4f){0.f,0.f,0.f,0.f};
    const int n = wcol;  // < 128
    #pragma unroll
    for (int kt = 0; kt < 8; ++kt){
      H8 b;
      const int k0 = kt*32 + quad*8;
      v4f f0 = *(const v4f*)(W_lat + n*256 + k0);
      v4f f1 = *(const v4f*)(W_lat + n*256 + k0 + 4);
      #pragma unroll
      for (int j = 0; j < 4; ++j){ b.h[j] = (_Float16)f0[j]; b.h[j+4] = (_Float16)f1[j]; }
      zacc = __builtin_amdgcn_mfma_f32_16x16x32_f16(Ah[kt].v, b.v, zacc, 0, 0, 0);
    }
    const float bl = b_lat[n];
    #pragma unroll
    for (int r = 0; r < 4; ++r){
      const int m = quad*4 + r;
      const float zv = zacc[r] + bl;
      __builtin_nontemporal_store(zv, dout + 11534336u + (u64)(g*16 + m)*128u + n);
      st_sc01(zb + m*128 + n, f2tag(zv, TAG(1024)));
    }
  }

  // ---- decoder init: h0 = z @ W_decinit.T + b_decinit (all 16 WGs) ----
  {
    H8 Az[4];
    read_tile128(zb, TAG(1024), c, quad, Az);
    const int n = wcol;
    v4f da = (v4f){0.f,0.f,0.f,0.f};
    #pragma unroll
    for (int kt = 0; kt < 4; ++kt){
      H8 b;
      const int k0 = kt*32 + quad*8;
      v4f f0 = *(const v4f*)(W_decinit + n*128 + k0);
      v4f f1 = *(const v4f*)(W_decinit + n*128 + k0 + 4);
      #pragma unroll
      for (int j = 0; j < 4; ++j){ b.h[j] = (_Float16)f0[j]; b.h[j+4] = (_Float16)f1[j]; }
      da = __builtin_amdgcn_mfma_f32_16x16x32_f16(Az[kt].v, b.v, da, 0, 0, 0);
    }
    const float bdi = b_decinit[n];
    u32* hw = hb + 2u*4096u;  // slot 2
    #pragma unroll
    for (int r = 0; r < 4; ++r){
      const float hv = da[r] + bdi;
      st_sc01(hw + (quad*4+r)*256 + wcol, f2tag(hv, TAG(1025)));
    }
  }

  #pragma unroll
  for (int r = 0; r < 4; ++r) cst[r] = 0.f;

  // ================= decoder =================
  #pragma unroll 1
  for (int t = 0; t < 1024; ++t){
    const u32 tg = TAG(1025 + t);
    const u32* src = (t == 0) ? (hb + 2u*4096u) : (hb + ((t-1)&1)*4096u);
    H8 Ah[8];
    read_tile256(src, tg, c, quad, Ah);

    if (t > 0){
      // pred(t-1) = sigmoid(W_out @ h(t-1) + b_out), redundant per WG
      v4f pacc[6];
      #pragma unroll
      for (int nt = 0; nt < 6; ++nt) pacc[nt] = (v4f){0.f,0.f,0.f,0.f};
      #pragma unroll
      for (int nt = 0; nt < 6; ++nt)
        #pragma unroll
        for (int kt = 0; kt < 8; ++kt){
          H8 b; b.u4 = woutlds[(nt*8 + kt)*64 + l];
          pacc[nt] = __builtin_amdgcn_mfma_f32_16x16x32_f16(Ah[kt].v, b.v, pacc[nt], 0, 0, 0);
        }
      const bool wr = (w < 11) && ((c >> 3) == (w & 1));
      #pragma unroll
      for (int nt = 0; nt < 6; ++nt)
        #pragma unroll
        for (int r = 0; r < 4; ++r){
          const float pv = fsig(pacc[nt][r] + bo[nt]);
          const int m = quad*4 + r;
          predlds[m*104 + nt*16 + c] = (_Float16)pv;
          if (wr && nt == (w >> 1))
            __builtin_nontemporal_store(pv,
              dout + ((u64)(g*16 + m)*1024u + (u64)(t-1))*88u + 8*w + (c & 7));
        }
    }
    __syncthreads();

    H8 Ap[3];
    if (t == 0){
      #pragma unroll
      for (int kt = 0; kt < 3; ++kt){ Ap[kt].q[0] = 0; Ap[kt].q[1] = 0; }
    } else {
      #pragma unroll
      for (int kt = 0; kt < 3; ++kt)
        Ap[kt].u4 = *(const v4u*)(&predlds[c*104 + kt*32 + quad*8]);
    }

    v4f acc[4];
    #pragma unroll
    for (int nt = 0; nt < 4; ++nt) acc[nt] = (v4f){0.f,0.f,0.f,0.f};
    #pragma unroll
    for (int kt = 0; kt < 3; ++kt)
      #pragma unroll
      for (int nt = 0; nt < 4; ++nt)
        acc[nt] = __builtin_amdgcn_mfma_f32_16x16x32_f16(Ap[kt].v, Bw[nt][kt], acc[nt], 0, 0, 0);
    #pragma unroll
    for (int kt = 0; kt < 8; ++kt)
      #pragma unroll
      for (int nt = 0; nt < 4; ++nt)
        acc[nt] = __builtin_amdgcn_mfma_f32_16x16x32_f16(Ah[kt].v, Bw[nt][kt+3], acc[nt], 0, 0, 0);

    u32* hw = hb + (t&1)*4096u;
    const u32 wtg = TAG(1026 + t);
    #pragma unroll
    for (int r = 0; r < 4; ++r){
      const float gi = acc[0][r] + bd[0];
      const float gf = acc[1][r] + bd[1];
      const float gg = acc[2][r] + bd[2];
      const float go = acc[3][r] + bd[3];
      const float cn = fsig(gf)*cst[r] + fsig(gi)*ftanh(gg);
      cst[r] = cn;
      const float hn = fsig(go)*ftanh(cn);
      st_sc01(hw + (quad*4+r)*256 + wcol, f2tag(hn, wtg));
    }
  }

  // ---- tail: pred(1023) -> output row 1023 ----
  {
    H8 Ah[8];
    read_tile256(hb + 4096u, TAG(2049), c, quad, Ah);
    v4f pacc[6];
    #pragma unroll
    for (int nt = 0; nt < 6; ++nt) pacc[nt] = (v4f){0.f,0.f,0.f,0.f};
    #pragma unroll
    for (int nt = 0; nt < 6; ++nt)
      #pragma unroll
      for (int kt = 0; kt < 8; ++kt){
        H8 b; b.u4 = woutlds[(nt*8 + kt)*64 + l];
        pacc[nt] = __builtin_amdgcn_mfma_f32_16x16x32_f16(Ah[kt].v, b.v, pacc[nt], 0, 0, 0);
      }
    const bool wr = (w < 11) && ((c >> 3) == (w & 1));
    if (wr){
      const int nt = w >> 1;
      #pragma unroll
      for (int r = 0; r < 4; ++r){
        const float pv = fsig(pacc[nt][r] + bo[nt]);
        const int m = quad*4 + r;
        __builtin_nontemporal_store(pv,
          dout + ((u64)(g*16 + m)*1024u + 1023u)*88u + 8*w + (c & 7));
      }
    }
  }
}

extern "C" void kernel_launch(void* const* d_in, const int* in_sizes, int n_in,
                              void* d_out, int out_size, void* d_ws, size_t ws_size,
                              hipStream_t stream){
  (void)in_sizes; (void)n_in; (void)out_size; (void)ws_size;
  hipLaunchKernelGGL(lstm_ae, dim3(128), dim3(64), 0, stream,
    (const float*)d_in[0],  (const float*)d_in[1],  (const float*)d_in[2],
    (const float*)d_in[3],  (const float*)d_in[4],  (const float*)d_in[5],
    (const float*)d_in[6],  (const float*)d_in[7],  (const float*)d_in[8],
    (const float*)d_in[9],  (const float*)d_in[10], (const float*)d_in[11],
    (const float*)d_in[12], (const float*)d_in[13], (const float*)d_in[14],
    (float*)d_out, (char*)d_ws);
}